// Round 9
// baseline (6301.643 us; speedup 1.0000x reference)
//
#include <hip/hip_runtime.h>

// GRU L=512, N=64, H=512, E=256, K=H+E=768. Persistent column-split kernel:
// 32 blocks x 256 threads; block b owns 16 output cols; fp16 weight slices
// LDS-resident (73.7 KB, XOR-swizzled). r4's proven per-wave flag protocol
// (relaxed agent-scope atomics, no fences, no __syncthreads in loop).
// Round 9 changes:
//  - deferred h publish: hx stores issue at end of phase 2; the drain
//    (vmcnt(0)) happens at the NEXT iteration's start, covered by the
//    r-gate e-MFMAs; flag stored after. out[t-1] written after the publish.
//  - rh publish drain covered by z/h~ cover compute + e(t+1) prefetch:
//    store rh (2 stores) -> cover MFMAs -> prefetch 8 e-loads ->
//    vmcnt(8) == "2 rh stores retired, prefetch still flying" (vmcnt
//    retires in issue order, m135); asm memory barriers pin the order.
//  - e fragments live in registers (aereg), refreshed once per step.
//  - CANARY (one-time, off critical path): per-XCD same-XCD L2 visibility
//    test (plain store -> agent flag -> buffer_inv -> plain reload) with
//    bounded spins; on failure reads 8 MB of `out` -> +8 MB FETCH_SIZE per
//    failing XCD. Decides whether round 10 can use L2-local exchange.
// Numerics: fp16 operands, f32 MFMA accum, f32 state (absmax 3.9e-3 r1-r8).

#define LSTEPS 512
#define NBATCH 64
#define HDIM   512
#define EDIM   256
#define KDIM   768
#define NBLK   32
#define TPB    256

typedef _Float16 f16x8 __attribute__((ext_vector_type(8)));
typedef float    f32x4 __attribute__((ext_vector_type(4)));
typedef unsigned long long u64;

#define MFMA __builtin_amdgcn_mfma_f32_16x16x32_f16

__device__ __forceinline__ float sigm(float x){ return 1.0f/(1.0f+__expf(-x)); }
__device__ __forceinline__ float tanh_fast(float x){
  float e = __expf(2.0f*x);
  return 1.0f - 2.0f/(e + 1.0f);
}
__device__ __forceinline__ unsigned f16b(float x){
  union { _Float16 h; unsigned short u; } c; c.h = (_Float16)x; return (unsigned)c.u;
}

__global__ void prep_w(const float* __restrict__ Wz, const float* __restrict__ Wr,
                       const float* __restrict__ Wh, _Float16* __restrict__ wbuf){
  int tid = blockIdx.x*256 + threadIdx.x;
  int g   = tid / (HDIM*KDIM);
  int rem = tid - g*(HDIM*KDIM);
  int j   = rem / KDIM;
  int k   = rem - j*KDIM;
  const float* W = (g==0) ? Wz : ((g==1) ? Wr : Wh);
  wbuf[tid] = (_Float16)W[(size_t)k*HDIM + j];
}

__global__ void prep_emb(const int* __restrict__ x, const float* __restrict__ emb,
                         _Float16* __restrict__ ebuf){
  int tid = blockIdx.x*256 + threadIdx.x;
  int k4  = tid & 63;
  int tn  = tid >> 6;
  int row = x[tn];
  const float4 v = *(const float4*)(emb + (size_t)row*EDIM + (k4<<2));
  union { _Float16 h[4]; uint2 u; } p;
  p.h[0] = (_Float16)v.x; p.h[1] = (_Float16)v.y;
  p.h[2] = (_Float16)v.z; p.h[3] = (_Float16)v.w;
  *(uint2*)(ebuf + (size_t)tn*EDIM + (k4<<2)) = p.u;
}

// Exchange store (rows n0..n0+3, col jcol) as write-through 4B agent atomics.
__device__ __forceinline__ void store_x(_Float16* buf, int jc2, int n0, int lane,
                                        float v0, float v1, float v2, float v3){
  unsigned p01 = f16b(v0) | (f16b(v1) << 16);
  unsigned p23 = f16b(v2) | (f16b(v3) << 16);
  unsigned q01 = __shfl_xor(p01, 1, 64);
  unsigned q23 = __shfl_xor(p23, 1, 64);
  unsigned w0, w1; int r0;
  if (lane & 1){
    w0 = (q23 & 0xffffu) | (p23 << 16);
    w1 = (q23 >> 16)     | (p23 & 0xffff0000u);
    r0 = n0 + 2;
  } else {
    w0 = (p01 & 0xffffu) | (q01 << 16);
    w1 = (p01 >> 16)     | (q01 & 0xffff0000u);
    r0 = n0;
  }
  __hip_atomic_store((unsigned*)(buf + (size_t)r0*HDIM + jc2),     w0,
                     __ATOMIC_RELAXED, __HIP_MEMORY_SCOPE_AGENT);
  __hip_atomic_store((unsigned*)(buf + (size_t)(r0+1)*HDIM + jc2), w1,
                     __ATOMIC_RELAXED, __HIP_MEMORY_SCOPE_AGENT);
}

// Poll 32 per-block flags (lane l polls flag[l&31]) until all >= target.
__device__ __forceinline__ void waitfl(const unsigned* fl, unsigned target){
  const int l31 = threadIdx.x & 31;
  for (;;){
    unsigned v = __hip_atomic_load(&fl[l31], __ATOMIC_RELAXED, __HIP_MEMORY_SCOPE_AGENT);
    if (__all(v >= target)) break;
  }
}

__global__ __launch_bounds__(TPB, 1) void gru_persist(
    const _Float16* __restrict__ wbuf,   // [3][512][768]
    const _Float16* __restrict__ ebuf,   // [L][64][256]
    const float* __restrict__ bz, const float* __restrict__ br, const float* __restrict__ bh,
    _Float16* __restrict__ hx,           // [64][512] fp16 exchange (h)
    _Float16* __restrict__ rhx,          // [64][512] fp16 exchange (r*h)
    unsigned* __restrict__ hfl,          // [4][32] per-wave h flags
    unsigned* __restrict__ rhfl,         // [4][32] per-wave rh flags
    unsigned* __restrict__ xcnt,         // [8] canary claim counters
    unsigned* __restrict__ cflag,        // [8*16] canary flags (64B stride)
    unsigned* __restrict__ cdata,        // [8*16] canary data  (64B stride)
    float* __restrict__ out)             // [L][64][512]
{
  __shared__ char wlds[3*16*1536];       // 73728 B
  __shared__ int s_role, s_burn;
  const int jbase = blockIdx.x * 16;

  for (int cidx = threadIdx.x; cidx < 3*16*96; cidx += TPB){
    int g   = cidx / (16*96);
    int rem = cidx - g*(16*96);
    int col = rem / 96;
    int kch = rem - col*96;
    const uint4 v = *(const uint4*)(wbuf + ((size_t)(g*HDIM + jbase + col))*KDIM + kch*8);
    int off = (((g*16 + col)*1536) + kch*16) ^ ((col & 7) << 4);
    *(uint4*)(wlds + off) = v;
  }
  __syncthreads();

  // ---------------- canary: same-XCD L2 visibility test (one-time) --------
  if (threadIdx.x == 0){
    unsigned xcd;
    asm volatile("s_getreg_b32 %0, hwreg(HW_REG_XCC_ID)" : "=s"(xcd));
    xcd &= 7;
    unsigned rank = __hip_atomic_fetch_add(&xcnt[xcd], 1u,
                        __ATOMIC_RELAXED, __HIP_MEMORY_SCOPE_AGENT);
    s_role = (rank == 0) ? (int)(xcd<<1) : ((rank == 1) ? (int)((xcd<<1)|1) : -1);
    s_burn = 0;
  }
  __syncthreads();
  {
    const int role = s_role;
    if (role >= 0 && (role & 1) == 0){           // writer block (rank 0 on xcd)
      if (threadIdx.x == 0){
        int xcd = role >> 1;
        *(volatile unsigned*)&cdata[xcd*16] = 0xC0FFEE00u + (unsigned)xcd;  // plain store
        asm volatile("s_waitcnt vmcnt(0)" ::: "memory");
        __hip_atomic_store(&cflag[xcd*16], 1u, __ATOMIC_RELAXED, __HIP_MEMORY_SCOPE_AGENT);
      }
    }
    if (role >= 0 && (role & 1) == 1){           // reader block (rank 1 on xcd)
      if (threadIdx.x == 0){
        int xcd = role >> 1;
        volatile unsigned* dp = &cdata[xcd*16];
        unsigned pre = *dp; (void)pre;           // pre-cache line in L1 (stale 0)
        int ok = 0;
        for (int i = 0; i < (1<<15); ++i){       // bounded agent poll
          if (__hip_atomic_load(&cflag[xcd*16], __ATOMIC_RELAXED,
                                __HIP_MEMORY_SCOPE_AGENT) == 1u){ ok = 1; break; }
        }
        unsigned v = 0;
        if (ok){
          asm volatile("buffer_inv" ::: "memory");            // invalidate L1
          asm volatile("s_waitcnt vmcnt(0)" ::: "memory");
          v = *dp;                                            // plain reload
        }
        s_burn = (ok && v == 0xC0FFEE00u + (unsigned)xcd) ? 0 : 1;
      }
      __syncthreads();
      if (s_burn && (threadIdx.x >> 6) == 0){    // FETCH beacon: read 8 MB of out
        const float* src = out + (size_t)(role >> 1) * 2097152;
        float acc = 0.f;
        for (int i = (threadIdx.x & 63); i < 2097152; i += 256)
          acc += src[i];
        asm volatile("" :: "v"(acc));
      }
      __syncthreads();
    }
  }
  // ------------------------------------------------------------------------

  const int lane = threadIdx.x & 63;
  const int wave = threadIdx.x >> 6;
  const int c15  = lane & 15;
  const int kgrp = lane >> 4;
  const int jcol = jbase + c15;
  const int jc2  = jcol & ~1;
  const int arow = wave*16 + c15;
  const int n0   = wave*16 + kgrp*4;
  const int swz  = (c15 & 7) << 4;
  const int linz = ((      c15)*1536) + kgrp*16;
  const int linr = ((16  + c15)*1536) + kgrp*16;
  const int linh = ((32  + c15)*1536) + kgrp*16;
  const float bzj = bz[jcol];
  const float brj = br[jcol];
  const float bhj = bh[jcol];
  unsigned* myhfl  = hfl  + wave*32;
  unsigned* myrhfl = rhfl + wave*32;
  const u64* hrow  = (const u64*)hx  + (size_t)arow*128 + kgrp*2;
  const u64* rhrow = (const u64*)rhx + (size_t)arow*128 + kgrp*2;
  float hreg[4] = {0.f, 0.f, 0.f, 0.f};

  u64 q[32];
  f16x8 aereg[8];

#define LOADX(BASE) do {                                                      \
    _Pragma("unroll")                                                         \
    for (int kc = 0; kc < 16; ++kc){                                          \
      q[2*kc]   = __hip_atomic_load((BASE) + kc*8,     __ATOMIC_RELAXED,      \
                                    __HIP_MEMORY_SCOPE_AGENT);                \
      q[2*kc+1] = __hip_atomic_load((BASE) + kc*8 + 1, __ATOMIC_RELAXED,      \
                                    __HIP_MEMORY_SCOPE_AGENT);                \
    }                                                                         \
  } while (0)

#define AFRAG(KC) ({ union { u64 d[2]; f16x8 v; } _a;                         \
                     _a.d[0] = q[2*(KC)]; _a.d[1] = q[2*(KC)+1]; _a.v; })

  // Prefetch e fragments for t = 0.
  {
    const _Float16* ae0 = ebuf + (size_t)arow*EDIM + kgrp*8;
    #pragma unroll
    for (int kc = 0; kc < 8; ++kc) aereg[kc] = *(const f16x8*)(ae0 + kc*32);
  }

  for (int t = 0; t < LSTEPS; ++t){
    // ---- publish h(t): stores issued last iter; drain covered by r e-part.
    f32x4 accr = {0.f,0.f,0.f,0.f};
    #pragma unroll
    for (int kc = 0; kc < 8; ++kc){
      f16x8 brv = *(const f16x8*)(wlds + ((linr + (16+kc)*64) ^ swz));
      accr = MFMA(aereg[kc], brv, accr, 0, 0, 0);
    }
    asm volatile("s_waitcnt vmcnt(0)" ::: "memory");   // hx(t) stores drained
    __builtin_amdgcn_sched_barrier(0);
    if (lane == 0)
      __hip_atomic_store(&myhfl[blockIdx.x], (unsigned)t,
                         __ATOMIC_RELAXED, __HIP_MEMORY_SCOPE_AGENT);
    if (t > 0){                                        // out[t-1], off the chain
      #pragma unroll
      for (int i = 0; i < 4; ++i)
        out[((size_t)(t-1)*NBATCH + (n0+i))*HDIM + jcol] = hreg[i];
    }

    // ---- phase 1: r gate h-part after h exchange.
    waitfl(myhfl, (unsigned)t);
    LOADX(hrow);
    #pragma unroll
    for (int kc = 0; kc < 16; ++kc){
      f16x8 brv = *(const f16x8*)(wlds + ((linr + kc*64) ^ swz));
      accr = MFMA(AFRAG(kc), brv, accr, 0, 0, 0);
    }
    float rh[4];
    #pragma unroll
    for (int i = 0; i < 4; ++i)
      rh[i] = sigm(accr[i] + brj) * hreg[i];
    store_x(rhx, jc2, n0, lane, rh[0], rh[1], rh[2], rh[3]);
    asm volatile("" ::: "memory");                     // pin: stores before cover

    // ---- cover rh drain: z h-part (q in regs) + z,h~ e-parts + e prefetch.
    f32x4 accz = {0.f,0.f,0.f,0.f};
    f32x4 acch = {0.f,0.f,0.f,0.f};
    #pragma unroll
    for (int kc = 0; kc < 16; ++kc){
      f16x8 bzv = *(const f16x8*)(wlds + ((linz + kc*64) ^ swz));
      accz = MFMA(AFRAG(kc), bzv, accz, 0, 0, 0);
    }
    #pragma unroll
    for (int kc = 0; kc < 8; ++kc){
      f16x8 bzv = *(const f16x8*)(wlds + ((linz + (16+kc)*64) ^ swz));
      f16x8 bhv = *(const f16x8*)(wlds + ((linh + (16+kc)*64) ^ swz));
      accz = MFMA(aereg[kc], bzv, accz, 0, 0, 0);
      acch = MFMA(aereg[kc], bhv, acch, 0, 0, 0);
    }
    {                                                  // e(t+1) -> aereg (aereg dead)
      const int tn = (t + 1 < LSTEPS) ? (t + 1) : t;
      const _Float16* aen = ebuf + ((size_t)tn*NBATCH + arow)*EDIM + kgrp*8;
      #pragma unroll
      for (int kc = 0; kc < 8; ++kc) aereg[kc] = *(const f16x8*)(aen + kc*32);
    }
    asm volatile("" ::: "memory");                     // pin: loads before waitcnt
    __builtin_amdgcn_sched_barrier(0);
    asm volatile("s_waitcnt vmcnt(8)" ::: "memory");   // 2 rh stores retired; 8 e-loads fly
    __builtin_amdgcn_sched_barrier(0);
    if (lane == 0)
      __hip_atomic_store(&myrhfl[blockIdx.x], (unsigned)(t + 1),
                         __ATOMIC_RELAXED, __HIP_MEMORY_SCOPE_AGENT);
    float zreg[4];
    #pragma unroll
    for (int i = 0; i < 4; ++i) zreg[i] = sigm(accz[i] + bzj);

    // ---- phase 2: h~ h-part after rh exchange; update h; issue hx stores.
    waitfl(myrhfl, (unsigned)(t + 1));
    LOADX(rhrow);
    #pragma unroll
    for (int kc = 0; kc < 16; ++kc){
      f16x8 bhv = *(const f16x8*)(wlds + ((linh + kc*64) ^ swz));
      acch = MFMA(AFRAG(kc), bhv, acch, 0, 0, 0);
    }
    #pragma unroll
    for (int i = 0; i < 4; ++i){
      float ht = tanh_fast(acch[i] + bhj);
      hreg[i] = hreg[i] + zreg[i]*(ht - hreg[i]);      // (1-z)h + z*h~
    }
    store_x(hx, jc2, n0, lane, hreg[0], hreg[1], hreg[2], hreg[3]);
    // drain + publish happen at the top of the next iteration
  }
  asm volatile("s_waitcnt vmcnt(0)" ::: "memory");
  #pragma unroll
  for (int i = 0; i < 4; ++i)
    out[((size_t)(LSTEPS-1)*NBATCH + (n0+i))*HDIM + jcol] = hreg[i];
#undef LOADX
#undef AFRAG
}

extern "C" void kernel_launch(void* const* d_in, const int* in_sizes, int n_in,
                              void* d_out, int out_size, void* d_ws, size_t ws_size,
                              hipStream_t stream) {
  const int*   x   = (const int*)  d_in[0];
  const float* emb = (const float*)d_in[1];
  const float* Wz  = (const float*)d_in[2];
  const float* bz  = (const float*)d_in[3];
  const float* Wr  = (const float*)d_in[4];
  const float* br  = (const float*)d_in[5];
  const float* Wh  = (const float*)d_in[6];
  const float* bh  = (const float*)d_in[7];
  float* out = (float*)d_out;
  char*  ws  = (char*)d_ws;

  size_t off = 0;
  unsigned* hfl   = (unsigned*)(ws + off); off += 4*32*4;                   // 512
  unsigned* rhfl  = (unsigned*)(ws + off); off += 4*32*4;                   // 512
  unsigned* xcnt  = (unsigned*)(ws + off); off += 64;                       // [8]
  unsigned* cflag = (unsigned*)(ws + off); off += 8*16*4;                   // 512
  unsigned* cdata = (unsigned*)(ws + off); off += 8*16*4;                   // 512
  _Float16* hx    = (_Float16*)(ws + off); off += (size_t)NBATCH*HDIM*2;    // 65536
  size_t zero_bytes = off;               // flags + canary + hx start at 0
  _Float16* rhx   = (_Float16*)(ws + off); off += (size_t)NBATCH*HDIM*2;    // 65536
  _Float16* wbuf  = (_Float16*)(ws + off); off += (size_t)3*HDIM*KDIM*2;    // 2359296
  _Float16* ebuf  = (_Float16*)(ws + off); off += (size_t)LSTEPS*NBATCH*EDIM*2; // 16777216

  hipMemsetAsync(ws, 0, zero_bytes, stream);

  prep_w  <<<(3*HDIM*KDIM)/256,          256, 0, stream>>>(Wz, Wr, Wh, wbuf);
  prep_emb<<<(LSTEPS*NBATCH*EDIM/4)/256, 256, 0, stream>>>(x, emb, ebuf);
  gru_persist<<<NBLK, TPB, 0, stream>>>(wbuf, ebuf, bz, br, bh,
                                        hx, rhx, hfl, rhfl,
                                        xcnt, cflag, cdata, out);
}

// Round 10
// 5920.512 us; speedup vs baseline: 1.0644x; 1.0644x over previous
//
#include <hip/hip_runtime.h>

// GRU L=512, N=64, H=512, E=256, K=H+E=768.
// Round 10: same-XCD L2 exchange with deadlock-proof dual-path fallback.
//  - 16 working blocks x 32 cols; 3x768x32 fp16 weight slice in LDS
//    (147.5 KB, XOR-swizzled) -> 1 block/CU forced; 128 launched blocks
//    land 16 per XCD; HW_REG_XCC_ID claim picks one XCD (pigeonhole ->
//    provably terminates; losers exit; work is placement-independent).
//  - FAST path: exchange data/flags via the winner XCD's SHARED L2:
//    producers use PLAIN stores (write-through L1, allocate dirty in L2 --
//    r7's bug was sc0/nt stores bypassing L2 while readers hit a stale
//    clean L2 line); consumers use buffer_inv + plain loads (data) and
//    sc0 loads (flag polls). Single physical copy -> no staleness.
//  - FALLBACK: every publish is dual: same data into separate MALL buffers
//    via agent-scope atomic stores (r4-proven), flags likewise. Consumers
//    poll the fast flag for a bounded budget; on timeout latch sticky fpd
//    and use MALL flags + MALL data copies. Flag and data share the same
//    visibility mechanism per path => observed flag implies valid data.
//    Correct under either cache hypothesis; cannot hang.
//  - r4 anti-race invariant: one vmcnt(0) per publish drains the wave's
//    exchange stores AND its prior-generation exchange loads.
// Numerics: fp16 operands, f32 MFMA accum, f32 state (absmax 3.9e-3 r1-r9).

#define LSTEPS 512
#define NBATCH 64
#define HDIM   512
#define EDIM   256
#define KDIM   768
#define NWORK  16
#define COLS   32
#define TPB    256
#define NLAUNCH 128
#define FASTBUDGET 300

typedef _Float16 f16x8 __attribute__((ext_vector_type(8)));
typedef float    f32x4 __attribute__((ext_vector_type(4)));
typedef unsigned long long u64;

#define MFMA __builtin_amdgcn_mfma_f32_16x16x32_f16

__device__ __forceinline__ float sigm(float x){ return 1.0f/(1.0f+__expf(-x)); }
__device__ __forceinline__ float tanh_fast(float x){
  float e = __expf(2.0f*x);
  return 1.0f - 2.0f/(e + 1.0f);
}
__device__ __forceinline__ unsigned f16b(float x){
  union { _Float16 h; unsigned short u; } c; c.h = (_Float16)x; return (unsigned)c.u;
}
__device__ __forceinline__ f16x8 AFU(u64 a, u64 b){
  union { u64 d[2]; f16x8 v; } c; c.d[0] = a; c.d[1] = b; return c.v;
}

// sc0 load = bypass (own) L1, read shared L2. Self-contained wait.
__device__ __forceinline__ unsigned ld_sc0_u32(const unsigned* a){
  unsigned r;
  asm volatile("global_load_dword %0, %1, off sc0\n\ts_waitcnt vmcnt(0)"
               : "=v"(r) : "v"(a) : "memory");
  return r;
}

__global__ void prep_w(const float* __restrict__ Wz, const float* __restrict__ Wr,
                       const float* __restrict__ Wh, _Float16* __restrict__ wbuf){
  int tid = blockIdx.x*256 + threadIdx.x;
  int g   = tid / (HDIM*KDIM);
  int rem = tid - g*(HDIM*KDIM);
  int j   = rem / KDIM;
  int k   = rem - j*KDIM;
  const float* W = (g==0) ? Wz : ((g==1) ? Wr : Wh);
  wbuf[tid] = (_Float16)W[(size_t)k*HDIM + j];
}

__global__ void prep_emb(const int* __restrict__ x, const float* __restrict__ emb,
                         _Float16* __restrict__ ebuf){
  int tid = blockIdx.x*256 + threadIdx.x;
  int k4  = tid & 63;
  int tn  = tid >> 6;
  int row = x[tn];
  const float4 v = *(const float4*)(emb + (size_t)row*EDIM + (k4<<2));
  union { _Float16 h[4]; uint2 u; } p;
  p.h[0] = (_Float16)v.x; p.h[1] = (_Float16)v.y;
  p.h[2] = (_Float16)v.z; p.h[3] = (_Float16)v.w;
  *(uint2*)(ebuf + (size_t)tn*EDIM + (k4<<2)) = p.u;
}

// Lane-pair repack of (rows n0..n0+3, col jcol) -> two aligned dwords.
__device__ __forceinline__ void pack2(int lane, float v0, float v1, float v2,
                                      float v3, unsigned* w0, unsigned* w1, int* r0){
  unsigned p01 = f16b(v0) | (f16b(v1) << 16);
  unsigned p23 = f16b(v2) | (f16b(v3) << 16);
  unsigned q01 = __shfl_xor(p01, 1, 64);
  unsigned q23 = __shfl_xor(p23, 1, 64);
  if (lane & 1){
    *w0 = (q23 & 0xffffu) | (p23 << 16);
    *w1 = (q23 >> 16)     | (p23 & 0xffff0000u);
    *r0 = 2;
  } else {
    *w0 = (p01 & 0xffffu) | (q01 << 16);
    *w1 = (p01 >> 16)     | (q01 & 0xffff0000u);
    *r0 = 0;
  }
}

// Dual exchange store: plain (L2 path) + agent atomic (MALL path).
__device__ __forceinline__ void store_dual(_Float16* bufL2, _Float16* bufM,
                                           int jc2, int n0, int lane,
                                           float v0, float v1, float v2, float v3){
  unsigned w0, w1; int rr;
  pack2(lane, v0, v1, v2, v3, &w0, &w1, &rr);
  int r0 = n0 + rr;
  *(unsigned*)(bufL2 + (size_t)r0*HDIM + jc2)     = w0;   // plain -> shared L2
  *(unsigned*)(bufL2 + (size_t)(r0+1)*HDIM + jc2) = w1;
  __hip_atomic_store((unsigned*)(bufM + (size_t)r0*HDIM + jc2),     w0,
                     __ATOMIC_RELAXED, __HIP_MEMORY_SCOPE_AGENT);   // -> MALL
  __hip_atomic_store((unsigned*)(bufM + (size_t)(r0+1)*HDIM + jc2), w1,
                     __ATOMIC_RELAXED, __HIP_MEMORY_SCOPE_AGENT);
}

// Wait for all 16 producer flags >= target. Returns 1 if fallback was used.
__device__ __forceinline__ int waitx(const unsigned* flL2, const unsigned* flM,
                                     unsigned target, int fpd){
  const int l15 = threadIdx.x & 15;
  if (!fpd){
    for (int i = 0; i < FASTBUDGET; ++i){
      unsigned v = ld_sc0_u32(flL2 + l15);
      if (__all((int)(v >= target))) return 0;          // fast path ok
    }
  }
  for (;;){
    unsigned v = __hip_atomic_load(flM + l15, __ATOMIC_RELAXED,
                                   __HIP_MEMORY_SCOPE_AGENT);
    if (__all((int)(v >= target))) break;
  }
  return 1;
}

__global__ __launch_bounds__(TPB, 1) void gru_persist(
    const _Float16* __restrict__ wbuf,   // [3][512][768]
    const _Float16* __restrict__ ebuf,   // [L][64][256]
    const float* __restrict__ bz, const float* __restrict__ br, const float* __restrict__ bh,
    _Float16* __restrict__ hxL, _Float16* __restrict__ hxM,    // [64][512] h
    _Float16* __restrict__ rhL, _Float16* __restrict__ rhM,    // [64][512] r*h
    unsigned* __restrict__ hflL, unsigned* __restrict__ hflM,  // [4][16]
    unsigned* __restrict__ rflL, unsigned* __restrict__ rflM,  // [4][16]
    unsigned* __restrict__ xcnt, unsigned* __restrict__ winner,
    float* __restrict__ out)             // [L][64][512]
{
  __shared__ char wlds[3*COLS*1536];     // 147456 B
  __shared__ int s_slot;

  // ---- XCD claim: first XCD to assemble NWORK blocks does the work.
  if (threadIdx.x == 0){
    unsigned xcd;
    asm volatile("s_getreg_b32 %0, hwreg(HW_REG_XCC_ID)" : "=s"(xcd));
    xcd &= 7;
    unsigned rank = __hip_atomic_fetch_add(&xcnt[xcd], 1u,
                        __ATOMIC_RELAXED, __HIP_MEMORY_SCOPE_AGENT);
    int slot = -1;
    if (rank < NWORK){
      if (rank == NWORK-1){
        unsigned exp = 0u;
        __hip_atomic_compare_exchange_strong(winner, &exp, xcd+1u,
            __ATOMIC_RELAXED, __ATOMIC_RELAXED, __HIP_MEMORY_SCOPE_AGENT);
      }
      unsigned w;
      do { w = __hip_atomic_load(winner, __ATOMIC_RELAXED,
                                 __HIP_MEMORY_SCOPE_AGENT); }
      while (w == 0u);                   // terminates: pigeonhole fills some XCD
      if (w == xcd+1u) slot = (int)rank;
    }
    s_slot = slot;
  }
  __syncthreads();
  const int slot = s_slot;
  if (slot < 0) return;

  // ---- stage weight slice -> LDS, XOR-swizzled.
  const int jbase = slot * COLS;
  for (int cidx = threadIdx.x; cidx < 3*COLS*96; cidx += TPB){
    int g   = cidx / (COLS*96);
    int rem = cidx - g*(COLS*96);
    int col = rem / 96;
    int kch = rem - col*96;
    const uint4 v = *(const uint4*)(wbuf + ((size_t)(g*HDIM + jbase + col))*KDIM + kch*8);
    int off = (((g*COLS + col)*1536) + kch*16) ^ ((col & 7) << 4);
    *(uint4*)(wlds + off) = v;
  }
  __syncthreads();                       // last barrier; loop below is per-wave

  const int lane = threadIdx.x & 63;
  const int wave = threadIdx.x >> 6;     // rows 16*wave..16*wave+15
  const int c15  = lane & 15;
  const int kgrp = lane >> 4;
  const int arow = wave*16 + c15;
  const int n0   = wave*16 + kgrp*4;
  const int swz  = (c15 & 7) << 4;
  const int jcol0 = jbase + c15;
  const int jcol1 = jbase + 16 + c15;
  const int jc20  = jcol0 & ~1;
  const int jc21  = jcol1 & ~1;
  const int lz0 = ((0*COLS + c15     )*1536) + kgrp*16;
  const int lz1 = ((0*COLS + c15 + 16)*1536) + kgrp*16;
  const int lr0 = ((1*COLS + c15     )*1536) + kgrp*16;
  const int lr1 = ((1*COLS + c15 + 16)*1536) + kgrp*16;
  const int lh0 = ((2*COLS + c15     )*1536) + kgrp*16;
  const int lh1 = ((2*COLS + c15 + 16)*1536) + kgrp*16;
  const float bzj0 = bz[jcol0], bzj1 = bz[jcol1];
  const float brj0 = br[jcol0], brj1 = br[jcol1];
  const float bhj0 = bh[jcol0], bhj1 = bh[jcol1];
  const u64* hrowL = (const u64*)hxL + (size_t)arow*128 + kgrp*2;  // + kc*8 (+1)
  const u64* hrowM = (const u64*)hxM + (size_t)arow*128 + kgrp*2;
  const u64* rrowL = (const u64*)rhL + (size_t)arow*128 + kgrp*2;
  const u64* rrowM = (const u64*)rhM + (size_t)arow*128 + kgrp*2;
  unsigned* myhflL = hflL + wave*NWORK;
  unsigned* myhflM = hflM + wave*NWORK;
  unsigned* myrflL = rflL + wave*NWORK;
  unsigned* myrflM = rflM + wave*NWORK;
  float hreg0[4] = {0,0,0,0}, hreg1[4] = {0,0,0,0};
  int fpd = 0;                           // sticky: fast path dead

  u64 q[32];
  f16x8 aereg[8];

#define LOADQ_FAST(BASE) do {                                                 \
    asm volatile("buffer_inv" ::: "memory");                                  \
    _Pragma("unroll")                                                         \
    for (int kc = 0; kc < 16; ++kc){                                          \
      q[2*kc]   = (BASE)[kc*8];                                               \
      q[2*kc+1] = (BASE)[kc*8 + 1];                                           \
    }                                                                         \
  } while (0)

#define LOADQ_MALL(BASE) do {                                                 \
    _Pragma("unroll")                                                         \
    for (int kc = 0; kc < 16; ++kc){                                          \
      q[2*kc]   = __hip_atomic_load((BASE) + kc*8,     __ATOMIC_RELAXED,      \
                                    __HIP_MEMORY_SCOPE_AGENT);                \
      q[2*kc+1] = __hip_atomic_load((BASE) + kc*8 + 1, __ATOMIC_RELAXED,      \
                                    __HIP_MEMORY_SCOPE_AGENT);                \
    }                                                                         \
  } while (0)

  // Prefetch e fragments for t = 0.
  {
    const _Float16* ae0 = ebuf + (size_t)arow*EDIM + kgrp*8;
    #pragma unroll
    for (int kc = 0; kc < 8; ++kc) aereg[kc] = *(const f16x8*)(ae0 + kc*32);
  }

  for (int t = 0; t < LSTEPS; ++t){
    const unsigned tagn = (unsigned)(t + 1);

    // ---- phase 1: r gate. e-part first (regs), then h exchange.
    f32x4 accr0 = {0,0,0,0}, accr1 = {0,0,0,0};
    #pragma unroll
    for (int kc = 0; kc < 8; ++kc){
      f16x8 b0 = *(const f16x8*)(wlds + ((lr0 + (16+kc)*64) ^ swz));
      f16x8 b1 = *(const f16x8*)(wlds + ((lr1 + (16+kc)*64) ^ swz));
      accr0 = MFMA(aereg[kc], b0, accr0, 0, 0, 0);
      accr1 = MFMA(aereg[kc], b1, accr1, 0, 0, 0);
    }
    {
      int fb = waitx(myhflL, myhflM, (unsigned)t, fpd);   // t=0: zeros pass
      fpd |= fb;
      if (fb) LOADQ_MALL(hrowM); else LOADQ_FAST(hrowL);
    }
    #pragma unroll
    for (int kc = 0; kc < 16; ++kc){
      f16x8 a  = AFU(q[2*kc], q[2*kc+1]);
      f16x8 b0 = *(const f16x8*)(wlds + ((lr0 + kc*64) ^ swz));
      f16x8 b1 = *(const f16x8*)(wlds + ((lr1 + kc*64) ^ swz));
      accr0 = MFMA(a, b0, accr0, 0, 0, 0);
      accr1 = MFMA(a, b1, accr1, 0, 0, 0);
    }
    float rh0[4], rh1[4];
    #pragma unroll
    for (int i = 0; i < 4; ++i){
      rh0[i] = sigm(accr0[i] + brj0) * hreg0[i];
      rh1[i] = sigm(accr1[i] + brj1) * hreg1[i];
    }
    store_dual(rhL, rhM, jc20, n0, lane, rh0[0], rh0[1], rh0[2], rh0[3]);
    store_dual(rhL, rhM, jc21, n0, lane, rh1[0], rh1[1], rh1[2], rh1[3]);
    asm volatile("s_waitcnt vmcnt(0)" ::: "memory");   // rh stores + h loads drained
    __builtin_amdgcn_sched_barrier(0);
    if (lane == 0){
      *(volatile unsigned*)&myrflL[slot] = tagn;       // plain -> shared L2
      __hip_atomic_store(&myrflM[slot], tagn,
                         __ATOMIC_RELAXED, __HIP_MEMORY_SCOPE_AGENT);
    }

    // ---- cover the rh round-trip: z (h frags in regs) + z,h~ e-parts.
    f32x4 accz0 = {0,0,0,0}, accz1 = {0,0,0,0};
    f32x4 acch0 = {0,0,0,0}, acch1 = {0,0,0,0};
    #pragma unroll
    for (int kc = 0; kc < 16; ++kc){
      f16x8 a  = AFU(q[2*kc], q[2*kc+1]);
      f16x8 b0 = *(const f16x8*)(wlds + ((lz0 + kc*64) ^ swz));
      f16x8 b1 = *(const f16x8*)(wlds + ((lz1 + kc*64) ^ swz));
      accz0 = MFMA(a, b0, accz0, 0, 0, 0);
      accz1 = MFMA(a, b1, accz1, 0, 0, 0);
    }
    #pragma unroll
    for (int kc = 0; kc < 8; ++kc){
      f16x8 z0 = *(const f16x8*)(wlds + ((lz0 + (16+kc)*64) ^ swz));
      f16x8 z1 = *(const f16x8*)(wlds + ((lz1 + (16+kc)*64) ^ swz));
      f16x8 h0 = *(const f16x8*)(wlds + ((lh0 + (16+kc)*64) ^ swz));
      f16x8 h1 = *(const f16x8*)(wlds + ((lh1 + (16+kc)*64) ^ swz));
      accz0 = MFMA(aereg[kc], z0, accz0, 0, 0, 0);
      accz1 = MFMA(aereg[kc], z1, accz1, 0, 0, 0);
      acch0 = MFMA(aereg[kc], h0, acch0, 0, 0, 0);
      acch1 = MFMA(aereg[kc], h1, acch1, 0, 0, 0);
    }
    float zreg0[4], zreg1[4];
    #pragma unroll
    for (int i = 0; i < 4; ++i){
      zreg0[i] = sigm(accz0[i] + bzj0);
      zreg1[i] = sigm(accz1[i] + bzj1);
    }

    // ---- phase 2: h~ h-part after rh exchange; epilogue; publish h.
    {
      int fb = waitx(myrflL, myrflM, tagn, fpd);
      fpd |= fb;
      if (fb) LOADQ_MALL(rrowM); else LOADQ_FAST(rrowL);
    }
    #pragma unroll
    for (int kc = 0; kc < 16; ++kc){
      f16x8 a  = AFU(q[2*kc], q[2*kc+1]);
      f16x8 b0 = *(const f16x8*)(wlds + ((lh0 + kc*64) ^ swz));
      f16x8 b1 = *(const f16x8*)(wlds + ((lh1 + kc*64) ^ swz));
      acch0 = MFMA(a, b0, acch0, 0, 0, 0);
      acch1 = MFMA(a, b1, acch1, 0, 0, 0);
    }
    #pragma unroll
    for (int i = 0; i < 4; ++i){
      float ht0 = tanh_fast(acch0[i] + bhj0);
      float ht1 = tanh_fast(acch1[i] + bhj1);
      hreg0[i] = hreg0[i] + zreg0[i]*(ht0 - hreg0[i]);
      hreg1[i] = hreg1[i] + zreg1[i]*(ht1 - hreg1[i]);
    }
    store_dual(hxL, hxM, jc20, n0, lane, hreg0[0], hreg0[1], hreg0[2], hreg0[3]);
    store_dual(hxL, hxM, jc21, n0, lane, hreg1[0], hreg1[1], hreg1[2], hreg1[3]);
    asm volatile("s_waitcnt vmcnt(0)" ::: "memory");   // h stores + rh loads drained
    __builtin_amdgcn_sched_barrier(0);
    if (lane == 0){
      *(volatile unsigned*)&myhflL[slot] = tagn;
      __hip_atomic_store(&myhflM[slot], tagn,
                         __ATOMIC_RELAXED, __HIP_MEMORY_SCOPE_AGENT);
    }

    // ---- off the critical path: out[t] + e(t+1) prefetch (drain later).
    #pragma unroll
    for (int i = 0; i < 4; ++i){
      int n = n0 + i;
      out[((size_t)t*NBATCH + n)*HDIM + jcol0] = hreg0[i];
      out[((size_t)t*NBATCH + n)*HDIM + jcol1] = hreg1[i];
    }
    if (t + 1 < LSTEPS){
      const _Float16* aen = ebuf + ((size_t)(t+1)*NBATCH + arow)*EDIM + kgrp*8;
      #pragma unroll
      for (int kc = 0; kc < 8; ++kc) aereg[kc] = *(const f16x8*)(aen + kc*32);
    }
  }
#undef LOADQ_FAST
#undef LOADQ_MALL
}

extern "C" void kernel_launch(void* const* d_in, const int* in_sizes, int n_in,
                              void* d_out, int out_size, void* d_ws, size_t ws_size,
                              hipStream_t stream) {
  const int*   x   = (const int*)  d_in[0];
  const float* emb = (const float*)d_in[1];
  const float* Wz  = (const float*)d_in[2];
  const float* bz  = (const float*)d_in[3];
  const float* Wr  = (const float*)d_in[4];
  const float* br  = (const float*)d_in[5];
  const float* Wh  = (const float*)d_in[6];
  const float* bh  = (const float*)d_in[7];
  float* out = (float*)d_out;
  char*  ws  = (char*)d_ws;

  size_t off = 0;
  unsigned* xcnt   = (unsigned*)(ws + off); off += 64;
  unsigned* winner = (unsigned*)(ws + off); off += 64;
  unsigned* hflL = (unsigned*)(ws + off); off += 4*NWORK*4;   // 256
  unsigned* hflM = (unsigned*)(ws + off); off += 4*NWORK*4;
  unsigned* rflL = (unsigned*)(ws + off); off += 4*NWORK*4;
  unsigned* rflM = (unsigned*)(ws + off); off += 4*NWORK*4;
  _Float16* hxL  = (_Float16*)(ws + off); off += (size_t)NBATCH*HDIM*2;  // 65536
  _Float16* hxM  = (_Float16*)(ws + off); off += (size_t)NBATCH*HDIM*2;
  size_t zero_bytes = off;               // claim + flags + h copies start at 0
  _Float16* rhL  = (_Float16*)(ws + off); off += (size_t)NBATCH*HDIM*2;
  _Float16* rhM  = (_Float16*)(ws + off); off += (size_t)NBATCH*HDIM*2;
  _Float16* wbuf = (_Float16*)(ws + off); off += (size_t)3*HDIM*KDIM*2;        // 2359296
  _Float16* ebuf = (_Float16*)(ws + off); off += (size_t)LSTEPS*NBATCH*EDIM*2; // 16777216

  hipMemsetAsync(ws, 0, zero_bytes, stream);

  prep_w  <<<(3*HDIM*KDIM)/256,          256, 0, stream>>>(Wz, Wr, Wh, wbuf);
  prep_emb<<<(LSTEPS*NBATCH*EDIM/4)/256, 256, 0, stream>>>(x, emb, ebuf);
  gru_persist<<<NLAUNCH, TPB, 0, stream>>>(wbuf, ebuf, bz, br, bh,
                                           hxL, hxM, rhL, rhM,
                                           hflL, hflM, rflL, rflM,
                                           xcnt, winner, out);
}